// Round 4
// baseline (354.983 us; speedup 1.0000x reference)
//
#include <hip/hip_runtime.h>

#define NB_HG 2048   // H*G = 32*64
#define DIM_N 128
#define DIM_D 128

// Numerics: per output element, strictly sequential ascending-d fp32 FMA
// (matches OpenBLAS sgemm / Eigen gebp / XLA-CPU per-element accumulation).
// LDS layout: Xt[d][pc], pc = n ^ (4*(d&7)) — conflict-free writes and reads.
__global__ __launch_bounds__(256, 2)
void qjl_sketch_kernel(const float* __restrict__ data,
                       const float* __restrict__ mask,
                       const float* __restrict__ proj,
                       int* __restrict__ out)
{
    __shared__ float Xt[DIM_D * DIM_N];  // 64 KB -> 2 blocks/CU

    const int type = blockIdx.x;   // 0: inlier s<128, 1: inlier s>=128, 2: outlier s<128
    const int hg   = blockIdx.y;
    const int tid  = threadIdx.x;

    // ---------- stage masked, transposed, swizzled X into LDS ----------
    {
        const int   d  = tid & 127;
        const int   nh = tid >> 7;                 // 0 or 1
        const float m  = mask[hg * DIM_D + d];     // exactly 0.0f or 1.0f
        const float w  = (type == 2) ? m : (1.0f - m);
        const float* Xs = data + (size_t)hg * (DIM_N * DIM_D) + d;
        const int   pcs = 4 * (d & 7);
        float* row = &Xt[d * DIM_N];
        #pragma unroll
        for (int g = 0; g < 16; ++g) {
            const int n0 = g * 8 + nh * 4;         // 4-aligned logical n block
            float4 v;
            v.x = Xs[(size_t)(n0 + 0) * DIM_D] * w;   // exact: w in {0,1}
            v.y = Xs[(size_t)(n0 + 1) * DIM_D] * w;
            v.z = Xs[(size_t)(n0 + 2) * DIM_D] * w;
            v.w = Xs[(size_t)(n0 + 3) * DIM_D] * w;
            *reinterpret_cast<float4*>(&row[n0 ^ pcs]) = v;
        }
    }
    __syncthreads();

    // ---------- register-tiled masked GEMM: 8n x 8s per thread ----------
    const int tn = tid & 15;                       // 16 n-groups
    const int ts = tid >> 4;                       // 16 s-groups
    const int N8 = tn * 8;
    const int s0 = ((type == 1) ? 128 : 0) + ts * 8;

    float acc[8][8];                               // [j: s-bit][i: n]
    #pragma unroll
    for (int j = 0; j < 8; ++j)
        #pragma unroll
        for (int i = 0; i < 8; ++i) acc[j][i] = 0.0f;

    const float* p[8];
    #pragma unroll
    for (int j = 0; j < 8; ++j) p[j] = proj + (size_t)(s0 + j) * DIM_D;

    for (int db = 0; db < DIM_D; db += 4) {
        // b-fragments: 8 projection rows, 4 consecutive d each (L2-resident)
        float4 b[8];
        #pragma unroll
        for (int j = 0; j < 8; ++j)
            b[j] = *reinterpret_cast<const float4*>(p[j] + db);

        #pragma unroll
        for (int dd = 0; dd < 4; ++dd) {           // ascending d within block
            const int d2 = db + dd;
            const int B8 = N8 ^ (8 * ((d2 >> 1) & 3));      // swizzled 8-block base
            const float* r = &Xt[d2 * DIM_N + B8];
            const float4 q0 = *reinterpret_cast<const float4*>(r);
            const float4 q1 = *reinterpret_cast<const float4*>(r + 4);
            float a[8];
            if (dd & 1) {   // d odd: halves swapped by swizzle bit 2 (compile-time)
                a[0]=q1.x; a[1]=q1.y; a[2]=q1.z; a[3]=q1.w;
                a[4]=q0.x; a[5]=q0.y; a[6]=q0.z; a[7]=q0.w;
            } else {
                a[0]=q0.x; a[1]=q0.y; a[2]=q0.z; a[3]=q0.w;
                a[4]=q1.x; a[5]=q1.y; a[6]=q1.z; a[7]=q1.w;
            }
            #pragma unroll
            for (int j = 0; j < 8; ++j) {
                const float bv = (dd == 0) ? b[j].x : (dd == 1) ? b[j].y
                               : (dd == 2) ? b[j].z : b[j].w;
                #pragma unroll
                for (int i = 0; i < 8; ++i)
                    acc[j][i] = fmaf(bv, a[i], acc[j][i]);   // serial dep: order fixed
            }
        }
    }

    // ---------- sign-pack (bit j = s0+j > 0) and store as int32 ----------
    const size_t inl_total = (size_t)NB_HG * DIM_N * 32;   // 8388608
    #pragma unroll
    for (int i = 0; i < 8; ++i) {
        int byte = 0;
        #pragma unroll
        for (int j = 0; j < 8; ++j)
            if (acc[j][i] > 0.0f) byte |= (1 << j);
        const int n = N8 + i;
        size_t idx;
        if (type == 2)
            idx = inl_total + ((size_t)hg * DIM_N + n) * 16 + ts;
        else
            idx = ((size_t)hg * DIM_N + n) * 32 + (type == 1 ? 16 : 0) + ts;
        out[idx] = byte;
    }
}

extern "C" void kernel_launch(void* const* d_in, const int* in_sizes, int n_in,
                              void* d_out, int out_size, void* d_ws, size_t ws_size,
                              hipStream_t stream) {
    const float* data = (const float*)d_in[0];   // (1,32,64,128,128) fp32
    const float* mask = (const float*)d_in[1];   // (1,32,64,128) fp32, values {0,1}
    const float* proj = (const float*)d_in[2];   // (256,128) fp32
    int* out = (int*)d_out;                      // 8388608 inlier + 4194304 outlier int32

    dim3 grid(3, NB_HG);
    qjl_sketch_kernel<<<grid, 256, 0, stream>>>(data, mask, proj, out);
}